// Round 18
// baseline (177.160 us; speedup 1.0000x reference)
//
#include <hip/hip_runtime.h>

constexpr int NN = 50000;   // nodes
constexpr int NE = 800000;  // edges
constexpr int NG = 64;      // graphs
constexpr int DI = 64;      // in dim
constexpr int DH = 128;     // hidden dim
constexpr int DO = 3;       // out dim

constexpr int SCAN_B = 256;
constexpr int NBK = 196;                  // dst buckets of 256 nodes (dst >> 8)
constexpr int CHUNK = 4096;               // edges per partition block
constexpr int NCH = (NE + CHUNK - 1) / CHUNK;  // 196 chunks
constexpr int BBTOT = NBK * NCH;          // 38416 (bucket-major [b][c])
constexpr int NBB = (BBTOT + 255) / 256;  // 151 scan blocks

typedef unsigned int u32;

// ---------------- bf16 helpers ----------------
__device__ inline float blo(u32 u) { return __uint_as_float(u << 16); }
__device__ inline float bhi(u32 u) { return __uint_as_float(u & 0xffff0000u); }
__device__ inline u32 f2b(float f) {  // RNE round to bf16 (16-bit pattern)
    u32 u = __float_as_uint(f);
    return (u + 0x7fffu + ((u >> 16) & 1u)) >> 16;
}
__device__ inline void fma8(float w, uint4 v, float acc[8]) {
    acc[0] = fmaf(w, blo(v.x), acc[0]); acc[1] = fmaf(w, bhi(v.x), acc[1]);
    acc[2] = fmaf(w, blo(v.y), acc[2]); acc[3] = fmaf(w, bhi(v.y), acc[3]);
    acc[4] = fmaf(w, blo(v.z), acc[4]); acc[5] = fmaf(w, bhi(v.z), acc[5]);
    acc[6] = fmaf(w, blo(v.w), acc[6]); acc[7] = fmaf(w, bhi(v.w), acc[7]);
}

// ---------------- fused: x->bf16, zero pooled, gstart bsearch ----------------
__global__ void k_init(const float* __restrict__ x, uint4* __restrict__ xb,
                       float* __restrict__ pooled, const int* __restrict__ batch,
                       int* __restrict__ gstart) {
    int i = blockIdx.x * blockDim.x + threadIdx.x;
    if (i < NN * DI / 8) {
        float4 a = reinterpret_cast<const float4*>(x)[i * 2];
        float4 b = reinterpret_cast<const float4*>(x)[i * 2 + 1];
        uint4 o;
        o.x = f2b(a.x) | (f2b(a.y) << 16);
        o.y = f2b(a.z) | (f2b(a.w) << 16);
        o.z = f2b(b.x) | (f2b(b.y) << 16);
        o.w = f2b(b.z) | (f2b(b.w) << 16);
        xb[i] = o;
    }
    if (i < NG * DH) pooled[i] = 0.0f;
    if (blockIdx.x == 0 && threadIdx.x <= NG) {
        int g = threadIdx.x;
        int lo = 0, hi = NN;
        while (lo < hi) {
            int mid = (lo + hi) >> 1;
            if (batch[mid] < g) lo = mid + 1; else hi = mid;
        }
        gstart[g] = lo;
    }
}

// ---------------- hist: per-(bucket,chunk) LDS counts ONLY (no global atomics) ----------------
__global__ __launch_bounds__(256) void k_histc(const int* __restrict__ dst,
                                               int* __restrict__ cntBB) {
    __shared__ int lcnt[NBK];
    const int t = threadIdx.x, c = blockIdx.x;
    for (int b = t; b < NBK; b += 256) lcnt[b] = 0;
    __syncthreads();
    const int base = c * CHUNK;
    const int endE = min(base + CHUNK, NE);
    for (int e = base + t; e < endE; e += 256) atomicAdd(&lcnt[dst[e] >> 8], 1);
    __syncthreads();
    for (int b = t; b < NBK; b += 256) cntBB[b * NCH + c] = lcnt[b];
}

// block-local inclusive scan helper over sm[256]
__device__ inline void blockScan(int* sm) {
    for (int off = 1; off < SCAN_B; off <<= 1) {
        int add = (threadIdx.x >= off) ? sm[threadIdx.x - off] : 0;
        __syncthreads();
        sm[threadIdx.x] += add;
        __syncthreads();
    }
}

// ---------------- cntBB block scans (in place) + per-block sums ----------------
__global__ void k_scanBB1(int* __restrict__ cntBB, int* __restrict__ bbpartial) {
    __shared__ int sm[SCAN_B];
    int i = blockIdx.x * SCAN_B + threadIdx.x;
    int v = (i < BBTOT) ? cntBB[i] : 0;
    sm[threadIdx.x] = v;
    __syncthreads();
    blockScan(sm);
    if (i < BBTOT) cntBB[i] = sm[threadIdx.x] - v;  // block-local exclusive
    if (threadIdx.x == SCAN_B - 1) bbpartial[blockIdx.x] = sm[SCAN_B - 1];
}

__global__ void k_scanB(int* __restrict__ bbpartial) {  // single block, NBB<=256
    __shared__ int sm[SCAN_B];
    int v = (threadIdx.x < NBB) ? bbpartial[threadIdx.x] : 0;
    sm[threadIdx.x] = v;
    __syncthreads();
    blockScan(sm);
    if (threadIdx.x < NBB) bbpartial[threadIdx.x] = sm[threadIdx.x] - v;  // exclusive
}

// ---------------- pass 2: bin (src | dst&255) into bucket-sorted stage via LDS cursors ----------------
__global__ __launch_bounds__(256) void k_fillP2(const int* __restrict__ src,
                                                const int* __restrict__ dst,
                                                const int* __restrict__ cntBB,
                                                const int* __restrict__ bbpartial,
                                                u32* __restrict__ stage) {
    __shared__ int lcur[NBK];
    const int t = threadIdx.x, c = blockIdx.x;
    for (int b = t; b < NBK; b += 256) {
        int i = b * NCH + c;
        lcur[b] = cntBB[i] + bbpartial[i >> 8];
    }
    __syncthreads();
    const int base = c * CHUNK;
    const int endE = min(base + CHUNK, NE);
    for (int e = base + t; e < endE; e += 256) {
        int s = src[e], d = dst[e];
        int slot = atomicAdd(&lcur[d >> 8], 1);
        stage[slot] = ((u32)(d & 255) << 16) | (u32)s;
    }
}

// ---------------- pass B: per-bucket LDS counting sort -> rowptr, dinv, csr16 ----------------
__global__ __launch_bounds__(256) void k_fillB(const u32* __restrict__ stage,
                                               const int* __restrict__ cntBB,
                                               const int* __restrict__ bbpartial,
                                               int* __restrict__ rowptr,
                                               float* __restrict__ dinv,
                                               ushort* __restrict__ csr16) {
    __shared__ int cnt[256];
    __shared__ int sm[256];
    __shared__ int cur[256];
    const int b = blockIdx.x, t = threadIdx.x;
    cnt[t] = 0;
    const int i0 = b * NCH;
    const int beg = cntBB[i0] + bbpartial[i0 >> 8];
    const int end = (b + 1 < NBK) ? cntBB[i0 + NCH] + bbpartial[(i0 + NCH) >> 8] : NE;
    __syncthreads();
    for (int i = beg + t; i < end; i += 256) atomicAdd(&cnt[(stage[i] >> 16) & 255u], 1);
    __syncthreads();
    const int v = cnt[t];
    sm[t] = v;
    __syncthreads();
    blockScan(sm);
    const int excl = sm[t] - v;
    const int n = b * 256 + t;
    if (n < NN) {
        rowptr[n] = beg + excl;
        dinv[n] = rsqrtf((float)(v + 1));  // +1 self-loop
    }
    if (b == NBK - 1 && t == 0) rowptr[NN] = NE;
    cur[t] = beg + excl;
    __syncthreads();
    for (int i = beg + t; i < end; i += 256) {
        u32 e = stage[i];
        int slot = atomicAdd(&cur[(e >> 16) & 255u], 1);
        csr16[slot] = (ushort)(e & 0xffffu);
    }
}

// ---------------- gather aggregation (zero LDS, high occupancy): u16 csr, w from dinv ----------------
template <int D, bool BIAS_RELU>
__global__ __launch_bounds__(256) void k_agge(const ushort* __restrict__ hb,
                                              const ushort* __restrict__ csr16,
                                              const int* __restrict__ rowptr,
                                              const float* __restrict__ dinv,
                                              const float* __restrict__ bias,
                                              u32* __restrict__ out) {
    constexpr int SUB = D / 8;        // lanes per node (8 for D=64, 16 for D=128)
    constexpr int NPB = 256 / SUB;    // nodes per block
    const int sub = threadIdx.x / SUB;
    const int sl = threadIdx.x % SUB;
    const int node = blockIdx.x * NPB + sub;
    if (node >= NN) return;

    const float dn = dinv[node];
    float acc[8];
    {
        uint4 v = *reinterpret_cast<const uint4*>(hb + (size_t)node * D + sl * 8);
        float w = dn * dn;
        acc[0] = w * blo(v.x); acc[1] = w * bhi(v.x);
        acc[2] = w * blo(v.y); acc[3] = w * bhi(v.y);
        acc[4] = w * blo(v.z); acc[5] = w * bhi(v.z);
        acc[6] = w * blo(v.w); acc[7] = w * bhi(v.w);
    }
    int j = rowptr[node];
    const int end = rowptr[node + 1];
    while ((j & 3) && j < end) {
        int s = csr16[j];
        uint4 g = *reinterpret_cast<const uint4*>(hb + (size_t)s * D + sl * 8);
        fma8(dn * dinv[s], g, acc);
        ++j;
    }
    for (; j + 4 <= end; j += 4) {
        ushort4 q = *reinterpret_cast<const ushort4*>(csr16 + j);
        uint4 g0 = *reinterpret_cast<const uint4*>(hb + (size_t)q.x * D + sl * 8);
        uint4 g1 = *reinterpret_cast<const uint4*>(hb + (size_t)q.y * D + sl * 8);
        uint4 g2 = *reinterpret_cast<const uint4*>(hb + (size_t)q.z * D + sl * 8);
        uint4 g3 = *reinterpret_cast<const uint4*>(hb + (size_t)q.w * D + sl * 8);
        float w0 = dn * dinv[q.x], w1 = dn * dinv[q.y];
        float w2 = dn * dinv[q.z], w3 = dn * dinv[q.w];
        fma8(w0, g0, acc);
        fma8(w1, g1, acc);
        fma8(w2, g2, acc);
        fma8(w3, g3, acc);
    }
    while (j < end) {
        int s = csr16[j];
        uint4 g = *reinterpret_cast<const uint4*>(hb + (size_t)s * D + sl * 8);
        fma8(dn * dinv[s], g, acc);
        ++j;
    }
    if (BIAS_RELU) {
        float4 b0 = *reinterpret_cast<const float4*>(bias + sl * 8);
        float4 b1v = *reinterpret_cast<const float4*>(bias + sl * 8 + 4);
        acc[0] = fmaxf(acc[0] + b0.x, 0.f); acc[1] = fmaxf(acc[1] + b0.y, 0.f);
        acc[2] = fmaxf(acc[2] + b0.z, 0.f); acc[3] = fmaxf(acc[3] + b0.w, 0.f);
        acc[4] = fmaxf(acc[4] + b1v.x, 0.f); acc[5] = fmaxf(acc[5] + b1v.y, 0.f);
        acc[6] = fmaxf(acc[6] + b1v.z, 0.f); acc[7] = fmaxf(acc[7] + b1v.w, 0.f);
    }
    uint4 o;
    o.x = f2b(acc[0]) | (f2b(acc[1]) << 16);
    o.y = f2b(acc[2]) | (f2b(acc[3]) << 16);
    o.z = f2b(acc[4]) | (f2b(acc[5]) << 16);
    o.w = f2b(acc[6]) | (f2b(acc[7]) << 16);
    *reinterpret_cast<uint4*>(reinterpret_cast<ushort*>(out) + (size_t)node * D + sl * 8) = o;
}

// ---------------- FUSED double GEMM with register-prefetched W staging ----------------
// agg1b bf16 -> GEMM W1+b1+relu -> (h1 bf16 in LDS, aliases sA) -> GEMM W2 -> tb bf16
__device__ inline float4 fmaf4(float s, float4 w, float4 a) {
    a.x = fmaf(s, w.x, a.x); a.y = fmaf(s, w.y, a.y);
    a.z = fmaf(s, w.z, a.z); a.w = fmaf(s, w.w, a.w);
    return a;
}

__global__ __launch_bounds__(256) void k_gemm12(const ushort* __restrict__ A,
                                                const float* __restrict__ W1,
                                                const float* __restrict__ b1,
                                                const float* __restrict__ W2,
                                                u32* __restrict__ T) {
    constexpr int AP = DI + 4;   // 68: sA f32 stride
    constexpr int KT = 32;
    __shared__ float sU[64 * AP];   // 17.4 KB: sA f32, then aliased as sH bf16 (16 KB)
    __shared__ float sW[KT * DH];   // 16 KB
    ushort* sH = reinterpret_cast<ushort*>(sU);
    const int t = threadIdx.x;
    const int row0 = blockIdx.x * 64;
    const int cg = t & 31;
    const int rg = t >> 5;

    // W tile source: tiles 0,1 from W1; 2..5 from W2
    auto wsrc = [&](int tile) -> const float4* {
        return (tile < 2) ? reinterpret_cast<const float4*>(W1 + tile * KT * DH)
                          : reinterpret_cast<const float4*>(W2 + (tile - 2) * KT * DH);
    };

    // prologue: prefetch W tile 0 into registers (overlaps A staging loads)
    float4 wreg[4];
    {
        const float4* Wg = wsrc(0);
#pragma unroll
        for (int i = 0; i < 4; ++i) wreg[i] = Wg[t + 256 * i];
    }
    // stage A (bf16 -> f32 LDS): 64 rows x 64 cols
    {
        const int row = t >> 2;       // 0..63
        const int q2 = (t & 3) * 2;   // uint4-pair index 0,2,4,6
        int gr = row0 + row;
#pragma unroll
        for (int u = 0; u < 2; ++u) {
            uint4 v = make_uint4(0u, 0u, 0u, 0u);
            if (gr < NN)
                v = *reinterpret_cast<const uint4*>(A + (size_t)gr * DI + (q2 + u) * 8);
            *reinterpret_cast<float4*>(&sU[row * AP + (q2 + u) * 8]) =
                make_float4(blo(v.x), bhi(v.x), blo(v.y), bhi(v.y));
            *reinterpret_cast<float4*>(&sU[row * AP + (q2 + u) * 8 + 4]) =
                make_float4(blo(v.z), bhi(v.z), blo(v.w), bhi(v.w));
        }
    }

    // ---- GEMM1: K=64 (tiles 0,1), +b1, relu -> h1 in registers
    float4 acc[8];
#pragma unroll
    for (int j = 0; j < 8; ++j) acc[j] = make_float4(0.f, 0.f, 0.f, 0.f);

#pragma unroll
    for (int tile = 0; tile < 2; ++tile) {
        __syncthreads();  // tile0: A-stage + wreg visible path; tile1: prev sW reads done
        {
            float4* sW4 = reinterpret_cast<float4*>(sW);
#pragma unroll
            for (int i = 0; i < 4; ++i) sW4[t + 256 * i] = wreg[i];
        }
        {   // prefetch next tile (tile+1 <= 2, always valid)
            const float4* Wg = wsrc(tile + 1);
#pragma unroll
            for (int i = 0; i < 4; ++i) wreg[i] = Wg[t + 256 * i];
        }
        __syncthreads();
#pragma unroll 2
        for (int kk = 0; kk < KT; kk += 4) {
            float4 w0 = *reinterpret_cast<const float4*>(&sW[(kk + 0) * DH + cg * 4]);
            float4 w1 = *reinterpret_cast<const float4*>(&sW[(kk + 1) * DH + cg * 4]);
            float4 w2 = *reinterpret_cast<const float4*>(&sW[(kk + 2) * DH + cg * 4]);
            float4 w3 = *reinterpret_cast<const float4*>(&sW[(kk + 3) * DH + cg * 4]);
#pragma unroll
            for (int j = 0; j < 8; ++j) {
                float4 a = *reinterpret_cast<const float4*>(&sU[(rg * 8 + j) * AP + tile * KT + kk]);
                acc[j] = fmaf4(a.x, w0, acc[j]);
                acc[j] = fmaf4(a.y, w1, acc[j]);
                acc[j] = fmaf4(a.z, w2, acc[j]);
                acc[j] = fmaf4(a.w, w3, acc[j]);
            }
        }
    }
    {
        float4 bb = *reinterpret_cast<const float4*>(b1 + cg * 4);
#pragma unroll
        for (int j = 0; j < 8; ++j) {
            acc[j].x = fmaxf(acc[j].x + bb.x, 0.f);
            acc[j].y = fmaxf(acc[j].y + bb.y, 0.f);
            acc[j].z = fmaxf(acc[j].z + bb.z, 0.f);
            acc[j].w = fmaxf(acc[j].w + bb.w, 0.f);
        }
    }

    // ---- GEMM2: K=128 (tiles 2..5) over sH bf16 -> tb bf16
    float4 acc2[8];
#pragma unroll
    for (int j = 0; j < 8; ++j) acc2[j] = make_float4(0.f, 0.f, 0.f, 0.f);

#pragma unroll
    for (int tile = 2; tile < 6; ++tile) {
        __syncthreads();  // tile2: all GEMM1 sU/sW reads done -> safe to overwrite alias
        if (tile == 2) {
            // write h1 (bf16) into sH (aliases sU)
#pragma unroll
            for (int j = 0; j < 8; ++j) {
                uint2 o = make_uint2(f2b(acc[j].x) | (f2b(acc[j].y) << 16),
                                     f2b(acc[j].z) | (f2b(acc[j].w) << 16));
                *reinterpret_cast<uint2*>(&sH[(rg * 8 + j) * DH + cg * 4]) = o;
            }
        }
        {
            float4* sW4 = reinterpret_cast<float4*>(sW);
#pragma unroll
            for (int i = 0; i < 4; ++i) sW4[t + 256 * i] = wreg[i];
        }
        if (tile < 5) {  // prefetch next W2 tile
            const float4* Wg = wsrc(tile + 1);
#pragma unroll
            for (int i = 0; i < 4; ++i) wreg[i] = Wg[t + 256 * i];
        }
        __syncthreads();
#pragma unroll 2
        for (int kk = 0; kk < KT; kk += 4) {
            float4 w0 = *reinterpret_cast<const float4*>(&sW[(kk + 0) * DH + cg * 4]);
            float4 w1 = *reinterpret_cast<const float4*>(&sW[(kk + 1) * DH + cg * 4]);
            float4 w2 = *reinterpret_cast<const float4*>(&sW[(kk + 2) * DH + cg * 4]);
            float4 w3 = *reinterpret_cast<const float4*>(&sW[(kk + 3) * DH + cg * 4]);
#pragma unroll
            for (int j = 0; j < 8; ++j) {
                uint2 av = *reinterpret_cast<const uint2*>(&sH[(rg * 8 + j) * DH + (tile - 2) * KT + kk]);
                acc2[j] = fmaf4(blo(av.x), w0, acc2[j]);
                acc2[j] = fmaf4(bhi(av.x), w1, acc2[j]);
                acc2[j] = fmaf4(blo(av.y), w2, acc2[j]);
                acc2[j] = fmaf4(bhi(av.y), w3, acc2[j]);
            }
        }
    }
#pragma unroll
    for (int j = 0; j < 8; ++j) {
        int gr = row0 + rg * 8 + j;
        if (gr < NN) {
            uint2 o = make_uint2(f2b(acc2[j].x) | (f2b(acc2[j].y) << 16),
                                 f2b(acc2[j].z) | (f2b(acc2[j].w) << 16));
            *reinterpret_cast<uint2*>(&T[(size_t)gr * (DH / 2) + cg * 2]) = o;
        }
    }
}

// ---------------- pooling (bf16 input, coalesced u32 reads) ----------------
constexpr int POOL_CHUNK = 64;
__global__ __launch_bounds__(256) void k_pool3(const u32* __restrict__ h2b,
                                               const int* __restrict__ batch,
                                               float* __restrict__ pooled) {
    const int c2 = threadIdx.x & 63;
    const int q = threadIdx.x >> 6;
    const int n0 = blockIdx.x * POOL_CHUNK;
    const int nEnd = min(n0 + POOL_CHUNK, NN);
    float a0 = 0.f, a1 = 0.f;
    int gcur = -1;
    for (int n = n0 + q; n < nEnd; n += 4) {
        int g = batch[n];
        if (g != gcur) {
            if (gcur >= 0) {
                atomicAdd(&pooled[gcur * DH + c2 * 2], a0);
                atomicAdd(&pooled[gcur * DH + c2 * 2 + 1], a1);
            }
            a0 = a1 = 0.f;
            gcur = g;
        }
        u32 v = h2b[(size_t)n * (DH / 2) + c2];
        a0 += blo(v);
        a1 += bhi(v);
    }
    if (gcur >= 0) {
        atomicAdd(&pooled[gcur * DH + c2 * 2], a0);
        atomicAdd(&pooled[gcur * DH + c2 * 2 + 1], a1);
    }
}

__global__ void k_head(const float* __restrict__ pooled, const int* __restrict__ gstart,
                       const float* __restrict__ Wf, const float* __restrict__ bf,
                       float* __restrict__ out) {
    int t = threadIdx.x;
    if (t >= NG * DO) return;
    int g = t / DO, o = t - g * DO;
    float acc = 0.0f;
    for (int k = 0; k < DH; ++k) acc += pooled[g * DH + k] * Wf[k * DO + o];
    float cnt = fmaxf((float)(gstart[g + 1] - gstart[g]), 1.0f);
    out[t] = acc / cnt + bf[o];
}

extern "C" void kernel_launch(void* const* d_in, const int* in_sizes, int n_in,
                              void* d_out, int out_size, void* d_ws, size_t ws_size,
                              hipStream_t stream) {
    const float* x   = (const float*)d_in[0];
    const int* ei    = (const int*)d_in[1];  // [2, NE] row-major
    const int* batch = (const int*)d_in[2];
    const float* W1  = (const float*)d_in[3];
    const float* b1  = (const float*)d_in[4];
    const float* W2  = (const float*)d_in[5];
    const float* b2  = (const float*)d_in[6];
    const float* Wf  = (const float*)d_in[7];
    const float* bf  = (const float*)d_in[8];
    float* out = (float*)d_out;

    const int* src = ei;
    const int* dst = ei + NE;

    // workspace (4B units; ~44 MB total)
    int* rowptr    = (int*)d_ws;               // 50056 (NN+1 used)
    int* bbpartial = rowptr + 50056;           // 256
    int* gstart    = bbpartial + 256;          // 80
    int* cntBB     = gstart + 80;              // 38416 ([b][c] bucket-major)
    ushort* csr16  = (ushort*)(cntBB + 38416); // NE u16 = 400000 u32
    float* dinv    = (float*)((u32*)(cntBB + 38416) + 400000);  // 50048
    u32* xbu       = (u32*)(dinv + 50048);     // 1.6M u32 (NN x 64 bf16)
    u32* stage     = xbu + 1600000;            // 0.8M u32 (NE packed entries)
    u32* agg1bu    = stage + 800000;           // 1.6M u32 (NN x 64 bf16)
    u32* tbu       = agg1bu + 1600000;         // 3.2M u32 (NN x 128 bf16)
    u32* h2b       = tbu + 3200000;            // 3.2M u32 (NN x 128 bf16)
    float* pooled  = (float*)(h2b + 3200000);  // 8192

    ushort* xb    = (ushort*)xbu;
    ushort* agg1b = (ushort*)agg1bu;
    ushort* tb    = (ushort*)tbu;

    const int B = 256;
    k_init<<<(NN * DI / 8 + B - 1) / B, B, 0, stream>>>(x, (uint4*)xb, pooled, batch, gstart);
    k_histc<<<NCH, 256, 0, stream>>>(dst, cntBB);
    k_scanBB1<<<NBB, SCAN_B, 0, stream>>>(cntBB, bbpartial);
    k_scanB<<<1, SCAN_B, 0, stream>>>(bbpartial);
    k_fillP2<<<NCH, 256, 0, stream>>>(src, dst, cntBB, bbpartial, stage);
    k_fillB<<<NBK, 256, 0, stream>>>(stage, cntBB, bbpartial, rowptr, dinv, csr16);

    const int gemmGrid = (NN + 63) / 64;  // 782

    // layer 1 agg (zero-LDS, high occupancy): gather xb -> agg1b bf16
    k_agge<DI, false><<<(NN + 31) / 32, 256, 0, stream>>>(xb, csr16, rowptr, dinv,
                                                          nullptr, agg1bu);
    // fused GEMM1+GEMM2 (register-prefetched W): agg1b -> h1 (LDS bf16) -> tb
    k_gemm12<<<gemmGrid, 256, 0, stream>>>(agg1b, W1, b1, W2, tbu);

    // layer-2 agg: gather tb, +b2, relu -> h2b (bf16)
    k_agge<DH, true><<<(NN + 15) / 16, 256, 0, stream>>>(tb, csr16, rowptr, dinv, b2, h2b);

    // pool + head
    k_pool3<<<(NN + POOL_CHUNK - 1) / POOL_CHUNK, 256, 0, stream>>>(h2b, batch, pooled);
    k_head<<<1, 256, 0, stream>>>(pooled, gstart, Wf, bf, out);
}

// Round 19
// 168.822 us; speedup vs baseline: 1.0494x; 1.0494x over previous
//
#include <hip/hip_runtime.h>

constexpr int NN = 50000;   // nodes
constexpr int NE = 800000;  // edges
constexpr int NG = 64;      // graphs
constexpr int DI = 64;      // in dim
constexpr int DH = 128;     // hidden dim
constexpr int DO = 3;       // out dim

constexpr int SCAN_B = 256;
constexpr int NBK = 196;                  // dst buckets of 256 nodes (dst >> 8)
constexpr int CHUNK = 4096;               // edges per partition block
constexpr int NCH = (NE + CHUNK - 1) / CHUNK;  // 196 chunks
constexpr int BBTOT = NBK * NCH;          // 38416 (bucket-major [b][c])
constexpr int NBB = (BBTOT + 255) / 256;  // 151 scan blocks

typedef unsigned int u32;

// ---------------- bf16 helpers ----------------
__device__ inline float blo(u32 u) { return __uint_as_float(u << 16); }
__device__ inline float bhi(u32 u) { return __uint_as_float(u & 0xffff0000u); }
__device__ inline u32 f2b(float f) {  // RNE round to bf16 (16-bit pattern)
    u32 u = __float_as_uint(f);
    return (u + 0x7fffu + ((u >> 16) & 1u)) >> 16;
}
__device__ inline void fma8(float w, uint4 v, float acc[8]) {
    acc[0] = fmaf(w, blo(v.x), acc[0]); acc[1] = fmaf(w, bhi(v.x), acc[1]);
    acc[2] = fmaf(w, blo(v.y), acc[2]); acc[3] = fmaf(w, bhi(v.y), acc[3]);
    acc[4] = fmaf(w, blo(v.z), acc[4]); acc[5] = fmaf(w, bhi(v.z), acc[5]);
    acc[6] = fmaf(w, blo(v.w), acc[6]); acc[7] = fmaf(w, bhi(v.w), acc[7]);
}

// ---------------- fused: x->bf16, zero pooled, gstart bsearch ----------------
__global__ void k_init(const float* __restrict__ x, uint4* __restrict__ xb,
                       float* __restrict__ pooled, const int* __restrict__ batch,
                       int* __restrict__ gstart) {
    int i = blockIdx.x * blockDim.x + threadIdx.x;
    if (i < NN * DI / 8) {
        float4 a = reinterpret_cast<const float4*>(x)[i * 2];
        float4 b = reinterpret_cast<const float4*>(x)[i * 2 + 1];
        uint4 o;
        o.x = f2b(a.x) | (f2b(a.y) << 16);
        o.y = f2b(a.z) | (f2b(a.w) << 16);
        o.z = f2b(b.x) | (f2b(b.y) << 16);
        o.w = f2b(b.z) | (f2b(b.w) << 16);
        xb[i] = o;
    }
    if (i < NG * DH) pooled[i] = 0.0f;
    if (blockIdx.x == 0 && threadIdx.x <= NG) {
        int g = threadIdx.x;
        int lo = 0, hi = NN;
        while (lo < hi) {
            int mid = (lo + hi) >> 1;
            if (batch[mid] < g) lo = mid + 1; else hi = mid;
        }
        gstart[g] = lo;
    }
}

// ---------------- hist: per-(bucket,chunk) LDS counts ONLY (no global atomics) ----------------
__global__ __launch_bounds__(256) void k_histc(const int* __restrict__ dst,
                                               int* __restrict__ cntBB) {
    __shared__ int lcnt[NBK];
    const int t = threadIdx.x, c = blockIdx.x;
    for (int b = t; b < NBK; b += 256) lcnt[b] = 0;
    __syncthreads();
    const int base = c * CHUNK;
    const int endE = min(base + CHUNK, NE);
    for (int e = base + t; e < endE; e += 256) atomicAdd(&lcnt[dst[e] >> 8], 1);
    __syncthreads();
    for (int b = t; b < NBK; b += 256) cntBB[b * NCH + c] = lcnt[b];
}

// block-local inclusive scan helper over sm[256]
__device__ inline void blockScan(int* sm) {
    for (int off = 1; off < SCAN_B; off <<= 1) {
        int add = (threadIdx.x >= off) ? sm[threadIdx.x - off] : 0;
        __syncthreads();
        sm[threadIdx.x] += add;
        __syncthreads();
    }
}

// ---------------- cntBB block scans (in place) + per-block sums ----------------
__global__ void k_scanBB1(int* __restrict__ cntBB, int* __restrict__ bbpartial) {
    __shared__ int sm[SCAN_B];
    int i = blockIdx.x * SCAN_B + threadIdx.x;
    int v = (i < BBTOT) ? cntBB[i] : 0;
    sm[threadIdx.x] = v;
    __syncthreads();
    blockScan(sm);
    if (i < BBTOT) cntBB[i] = sm[threadIdx.x] - v;  // block-local exclusive
    if (threadIdx.x == SCAN_B - 1) bbpartial[blockIdx.x] = sm[SCAN_B - 1];
}

__global__ void k_scanB(int* __restrict__ bbpartial) {  // single block, NBB<=256
    __shared__ int sm[SCAN_B];
    int v = (threadIdx.x < NBB) ? bbpartial[threadIdx.x] : 0;
    sm[threadIdx.x] = v;
    __syncthreads();
    blockScan(sm);
    if (threadIdx.x < NBB) bbpartial[threadIdx.x] = sm[threadIdx.x] - v;  // exclusive
}

// ---------------- pass 2: bin (src | dst&255) into bucket-sorted stage via LDS cursors ----------------
__global__ __launch_bounds__(256) void k_fillP2(const int* __restrict__ src,
                                                const int* __restrict__ dst,
                                                const int* __restrict__ cntBB,
                                                const int* __restrict__ bbpartial,
                                                u32* __restrict__ stage) {
    __shared__ int lcur[NBK];
    const int t = threadIdx.x, c = blockIdx.x;
    for (int b = t; b < NBK; b += 256) {
        int i = b * NCH + c;
        lcur[b] = cntBB[i] + bbpartial[i >> 8];
    }
    __syncthreads();
    const int base = c * CHUNK;
    const int endE = min(base + CHUNK, NE);
    for (int e = base + t; e < endE; e += 256) {
        int s = src[e], d = dst[e];
        int slot = atomicAdd(&lcur[d >> 8], 1);
        stage[slot] = ((u32)(d & 255) << 16) | (u32)s;
    }
}

// ---------------- pass B: per-bucket LDS counting sort -> rowptr, dinv, csr16 ----------------
__global__ __launch_bounds__(256) void k_fillB(const u32* __restrict__ stage,
                                               const int* __restrict__ cntBB,
                                               const int* __restrict__ bbpartial,
                                               int* __restrict__ rowptr,
                                               float* __restrict__ dinv,
                                               ushort* __restrict__ csr16) {
    __shared__ int cnt[256];
    __shared__ int sm[256];
    __shared__ int cur[256];
    const int b = blockIdx.x, t = threadIdx.x;
    cnt[t] = 0;
    const int i0 = b * NCH;
    const int beg = cntBB[i0] + bbpartial[i0 >> 8];
    const int end = (b + 1 < NBK) ? cntBB[i0 + NCH] + bbpartial[(i0 + NCH) >> 8] : NE;
    __syncthreads();
    for (int i = beg + t; i < end; i += 256) atomicAdd(&cnt[(stage[i] >> 16) & 255u], 1);
    __syncthreads();
    const int v = cnt[t];
    sm[t] = v;
    __syncthreads();
    blockScan(sm);
    const int excl = sm[t] - v;
    const int n = b * 256 + t;
    if (n < NN) {
        rowptr[n] = beg + excl;
        dinv[n] = rsqrtf((float)(v + 1));  // +1 self-loop
    }
    if (b == NBK - 1 && t == 0) rowptr[NN] = NE;
    cur[t] = beg + excl;
    __syncthreads();
    for (int i = beg + t; i < end; i += 256) {
        u32 e = stage[i];
        int slot = atomicAdd(&cur[(e >> 16) & 255u], 1);
        csr16[slot] = (ushort)(e & 0xffffu);
    }
}

// ---------------- gather aggregation (zero LDS, high occupancy): u16 csr, w from dinv ----------------
template <int D, bool BIAS_RELU>
__global__ __launch_bounds__(256) void k_agge(const ushort* __restrict__ hb,
                                              const ushort* __restrict__ csr16,
                                              const int* __restrict__ rowptr,
                                              const float* __restrict__ dinv,
                                              const float* __restrict__ bias,
                                              u32* __restrict__ out) {
    constexpr int SUB = D / 8;        // lanes per node (8 for D=64, 16 for D=128)
    constexpr int NPB = 256 / SUB;    // nodes per block
    const int sub = threadIdx.x / SUB;
    const int sl = threadIdx.x % SUB;
    const int node = blockIdx.x * NPB + sub;
    if (node >= NN) return;

    const float dn = dinv[node];
    float acc[8];
    {
        uint4 v = *reinterpret_cast<const uint4*>(hb + (size_t)node * D + sl * 8);
        float w = dn * dn;
        acc[0] = w * blo(v.x); acc[1] = w * bhi(v.x);
        acc[2] = w * blo(v.y); acc[3] = w * bhi(v.y);
        acc[4] = w * blo(v.z); acc[5] = w * bhi(v.z);
        acc[6] = w * blo(v.w); acc[7] = w * bhi(v.w);
    }
    int j = rowptr[node];
    const int end = rowptr[node + 1];
    while ((j & 3) && j < end) {
        int s = csr16[j];
        uint4 g = *reinterpret_cast<const uint4*>(hb + (size_t)s * D + sl * 8);
        fma8(dn * dinv[s], g, acc);
        ++j;
    }
    for (; j + 4 <= end; j += 4) {
        ushort4 q = *reinterpret_cast<const ushort4*>(csr16 + j);
        uint4 g0 = *reinterpret_cast<const uint4*>(hb + (size_t)q.x * D + sl * 8);
        uint4 g1 = *reinterpret_cast<const uint4*>(hb + (size_t)q.y * D + sl * 8);
        uint4 g2 = *reinterpret_cast<const uint4*>(hb + (size_t)q.z * D + sl * 8);
        uint4 g3 = *reinterpret_cast<const uint4*>(hb + (size_t)q.w * D + sl * 8);
        float w0 = dn * dinv[q.x], w1 = dn * dinv[q.y];
        float w2 = dn * dinv[q.z], w3 = dn * dinv[q.w];
        fma8(w0, g0, acc);
        fma8(w1, g1, acc);
        fma8(w2, g2, acc);
        fma8(w3, g3, acc);
    }
    while (j < end) {
        int s = csr16[j];
        uint4 g = *reinterpret_cast<const uint4*>(hb + (size_t)s * D + sl * 8);
        fma8(dn * dinv[s], g, acc);
        ++j;
    }
    if (BIAS_RELU) {
        float4 b0 = *reinterpret_cast<const float4*>(bias + sl * 8);
        float4 b1v = *reinterpret_cast<const float4*>(bias + sl * 8 + 4);
        acc[0] = fmaxf(acc[0] + b0.x, 0.f); acc[1] = fmaxf(acc[1] + b0.y, 0.f);
        acc[2] = fmaxf(acc[2] + b0.z, 0.f); acc[3] = fmaxf(acc[3] + b0.w, 0.f);
        acc[4] = fmaxf(acc[4] + b1v.x, 0.f); acc[5] = fmaxf(acc[5] + b1v.y, 0.f);
        acc[6] = fmaxf(acc[6] + b1v.z, 0.f); acc[7] = fmaxf(acc[7] + b1v.w, 0.f);
    }
    uint4 o;
    o.x = f2b(acc[0]) | (f2b(acc[1]) << 16);
    o.y = f2b(acc[2]) | (f2b(acc[3]) << 16);
    o.z = f2b(acc[4]) | (f2b(acc[5]) << 16);
    o.w = f2b(acc[6]) | (f2b(acc[7]) << 16);
    *reinterpret_cast<uint4*>(reinterpret_cast<ushort*>(out) + (size_t)node * D + sl * 8) = o;
}

// ---------------- FUSED double GEMM (bf16 sA union, 32KB LDS, no prefetch) ----------------
// agg1b bf16 -> GEMM W1+b1+relu -> (h1 bf16 in same LDS union) -> GEMM W2 -> tb bf16
__device__ inline float4 fmaf4(float s, float4 w, float4 a) {
    a.x = fmaf(s, w.x, a.x); a.y = fmaf(s, w.y, a.y);
    a.z = fmaf(s, w.z, a.z); a.w = fmaf(s, w.w, a.w);
    return a;
}

__global__ __launch_bounds__(256) void k_gemm12(const ushort* __restrict__ A,
                                                const float* __restrict__ W1,
                                                const float* __restrict__ b1,
                                                const float* __restrict__ W2,
                                                u32* __restrict__ T) {
    constexpr int ASTR = 72;     // sA bf16 row stride (ushorts)
    constexpr int KT = 32;
    __shared__ ushort sU16[64 * DH];  // 16 KB union: sA bf16 [64][72] then sH bf16 [64][128]
    __shared__ float sW[KT * DH];     // 16 KB
    const int t = threadIdx.x;
    const int row0 = blockIdx.x * 64;
    const int cg = t & 31;
    const int rg = t >> 5;

    // ---- stage A (bf16, straight copy): 64 rows x 64 cols
    {
        const int row = t >> 2;      // 0..63
        const int q = t & 3;         // 16-ushort quarter
        int gr = row0 + row;
        uint4 v0 = make_uint4(0u, 0u, 0u, 0u), v1 = v0;
        if (gr < NN) {
            const uint4* Ag = reinterpret_cast<const uint4*>(A + (size_t)gr * DI + q * 16);
            v0 = Ag[0];
            v1 = Ag[1];
        }
        *reinterpret_cast<uint4*>(&sU16[row * ASTR + q * 16]) = v0;
        *reinterpret_cast<uint4*>(&sU16[row * ASTR + q * 16 + 8]) = v1;
    }

    // ---- GEMM1: K=64 (2 tiles of 32), +b1, relu -> h1 in registers
    float4 acc[8];
#pragma unroll
    for (int j = 0; j < 8; ++j) acc[j] = make_float4(0.f, 0.f, 0.f, 0.f);

#pragma unroll
    for (int tile = 0; tile < 2; ++tile) {
        __syncthreads();  // tile0: sA ready; tile1: prev sW reads done
        {
            const float4* Wg = reinterpret_cast<const float4*>(W1 + tile * KT * DH);
            float4* sW4 = reinterpret_cast<float4*>(sW);
#pragma unroll
            for (int i = 0; i < 4; ++i) sW4[t + 256 * i] = Wg[t + 256 * i];
        }
        __syncthreads();
#pragma unroll 2
        for (int kk = 0; kk < KT; kk += 4) {
            float4 w0 = *reinterpret_cast<const float4*>(&sW[(kk + 0) * DH + cg * 4]);
            float4 w1 = *reinterpret_cast<const float4*>(&sW[(kk + 1) * DH + cg * 4]);
            float4 w2 = *reinterpret_cast<const float4*>(&sW[(kk + 2) * DH + cg * 4]);
            float4 w3 = *reinterpret_cast<const float4*>(&sW[(kk + 3) * DH + cg * 4]);
#pragma unroll
            for (int j = 0; j < 8; ++j) {
                uint2 av = *reinterpret_cast<const uint2*>(&sU16[(rg * 8 + j) * ASTR + tile * KT + kk]);
                acc[j] = fmaf4(blo(av.x), w0, acc[j]);
                acc[j] = fmaf4(bhi(av.x), w1, acc[j]);
                acc[j] = fmaf4(blo(av.y), w2, acc[j]);
                acc[j] = fmaf4(bhi(av.y), w3, acc[j]);
            }
        }
    }
    {
        float4 bb = *reinterpret_cast<const float4*>(b1 + cg * 4);
#pragma unroll
        for (int j = 0; j < 8; ++j) {
            acc[j].x = fmaxf(acc[j].x + bb.x, 0.f);
            acc[j].y = fmaxf(acc[j].y + bb.y, 0.f);
            acc[j].z = fmaxf(acc[j].z + bb.z, 0.f);
            acc[j].w = fmaxf(acc[j].w + bb.w, 0.f);
        }
    }

    // ---- h1 (bf16) -> sH (same union; all sA reads complete first)
    __syncthreads();
#pragma unroll
    for (int j = 0; j < 8; ++j) {
        uint2 o = make_uint2(f2b(acc[j].x) | (f2b(acc[j].y) << 16),
                             f2b(acc[j].z) | (f2b(acc[j].w) << 16));
        *reinterpret_cast<uint2*>(&sU16[(rg * 8 + j) * DH + cg * 4]) = o;
    }

    // ---- GEMM2: K=128 (4 tiles of 32) over sH bf16 -> tb bf16
    float4 acc2[8];
#pragma unroll
    for (int j = 0; j < 8; ++j) acc2[j] = make_float4(0.f, 0.f, 0.f, 0.f);

#pragma unroll
    for (int tile = 0; tile < 4; ++tile) {
        __syncthreads();  // tile0: sH writes visible; else: prev sW reads done
        {
            const float4* Wg = reinterpret_cast<const float4*>(W2 + tile * KT * DH);
            float4* sW4 = reinterpret_cast<float4*>(sW);
#pragma unroll
            for (int i = 0; i < 4; ++i) sW4[t + 256 * i] = Wg[t + 256 * i];
        }
        __syncthreads();
#pragma unroll 2
        for (int kk = 0; kk < KT; kk += 4) {
            float4 w0 = *reinterpret_cast<const float4*>(&sW[(kk + 0) * DH + cg * 4]);
            float4 w1 = *reinterpret_cast<const float4*>(&sW[(kk + 1) * DH + cg * 4]);
            float4 w2 = *reinterpret_cast<const float4*>(&sW[(kk + 2) * DH + cg * 4]);
            float4 w3 = *reinterpret_cast<const float4*>(&sW[(kk + 3) * DH + cg * 4]);
#pragma unroll
            for (int j = 0; j < 8; ++j) {
                uint2 av = *reinterpret_cast<const uint2*>(&sU16[(rg * 8 + j) * DH + tile * KT + kk]);
                acc2[j] = fmaf4(blo(av.x), w0, acc2[j]);
                acc2[j] = fmaf4(bhi(av.x), w1, acc2[j]);
                acc2[j] = fmaf4(blo(av.y), w2, acc2[j]);
                acc2[j] = fmaf4(bhi(av.y), w3, acc2[j]);
            }
        }
    }
#pragma unroll
    for (int j = 0; j < 8; ++j) {
        int gr = row0 + rg * 8 + j;
        if (gr < NN) {
            uint2 o = make_uint2(f2b(acc2[j].x) | (f2b(acc2[j].y) << 16),
                                 f2b(acc2[j].z) | (f2b(acc2[j].w) << 16));
            *reinterpret_cast<uint2*>(&T[(size_t)gr * (DH / 2) + cg * 2]) = o;
        }
    }
}

// ---------------- pooling (bf16 input, coalesced u32 reads) ----------------
constexpr int POOL_CHUNK = 64;
__global__ __launch_bounds__(256) void k_pool3(const u32* __restrict__ h2b,
                                               const int* __restrict__ batch,
                                               float* __restrict__ pooled) {
    const int c2 = threadIdx.x & 63;
    const int q = threadIdx.x >> 6;
    const int n0 = blockIdx.x * POOL_CHUNK;
    const int nEnd = min(n0 + POOL_CHUNK, NN);
    float a0 = 0.f, a1 = 0.f;
    int gcur = -1;
    for (int n = n0 + q; n < nEnd; n += 4) {
        int g = batch[n];
        if (g != gcur) {
            if (gcur >= 0) {
                atomicAdd(&pooled[gcur * DH + c2 * 2], a0);
                atomicAdd(&pooled[gcur * DH + c2 * 2 + 1], a1);
            }
            a0 = a1 = 0.f;
            gcur = g;
        }
        u32 v = h2b[(size_t)n * (DH / 2) + c2];
        a0 += blo(v);
        a1 += bhi(v);
    }
    if (gcur >= 0) {
        atomicAdd(&pooled[gcur * DH + c2 * 2], a0);
        atomicAdd(&pooled[gcur * DH + c2 * 2 + 1], a1);
    }
}

__global__ void k_head(const float* __restrict__ pooled, const int* __restrict__ gstart,
                       const float* __restrict__ Wf, const float* __restrict__ bf,
                       float* __restrict__ out) {
    int t = threadIdx.x;
    if (t >= NG * DO) return;
    int g = t / DO, o = t - g * DO;
    float acc = 0.0f;
    for (int k = 0; k < DH; ++k) acc += pooled[g * DH + k] * Wf[k * DO + o];
    float cnt = fmaxf((float)(gstart[g + 1] - gstart[g]), 1.0f);
    out[t] = acc / cnt + bf[o];
}

extern "C" void kernel_launch(void* const* d_in, const int* in_sizes, int n_in,
                              void* d_out, int out_size, void* d_ws, size_t ws_size,
                              hipStream_t stream) {
    const float* x   = (const float*)d_in[0];
    const int* ei    = (const int*)d_in[1];  // [2, NE] row-major
    const int* batch = (const int*)d_in[2];
    const float* W1  = (const float*)d_in[3];
    const float* b1  = (const float*)d_in[4];
    const float* W2  = (const float*)d_in[5];
    const float* b2  = (const float*)d_in[6];
    const float* Wf  = (const float*)d_in[7];
    const float* bf  = (const float*)d_in[8];
    float* out = (float*)d_out;

    const int* src = ei;
    const int* dst = ei + NE;

    // workspace (4B units; ~44 MB total)
    int* rowptr    = (int*)d_ws;               // 50056 (NN+1 used)
    int* bbpartial = rowptr + 50056;           // 256
    int* gstart    = bbpartial + 256;          // 80
    int* cntBB     = gstart + 80;              // 38416 ([b][c] bucket-major)
    ushort* csr16  = (ushort*)(cntBB + 38416); // NE u16 = 400000 u32
    float* dinv    = (float*)((u32*)(cntBB + 38416) + 400000);  // 50048
    u32* xbu       = (u32*)(dinv + 50048);     // 1.6M u32 (NN x 64 bf16)
    u32* stage     = xbu + 1600000;            // 0.8M u32 (NE packed entries)
    u32* agg1bu    = stage + 800000;           // 1.6M u32 (NN x 64 bf16)
    u32* tbu       = agg1bu + 1600000;         // 3.2M u32 (NN x 128 bf16)
    u32* h2b       = tbu + 3200000;            // 3.2M u32 (NN x 128 bf16)
    float* pooled  = (float*)(h2b + 3200000);  // 8192

    ushort* xb    = (ushort*)xbu;
    ushort* agg1b = (ushort*)agg1bu;
    ushort* tb    = (ushort*)tbu;

    const int B = 256;
    k_init<<<(NN * DI / 8 + B - 1) / B, B, 0, stream>>>(x, (uint4*)xb, pooled, batch, gstart);
    k_histc<<<NCH, 256, 0, stream>>>(dst, cntBB);
    k_scanBB1<<<NBB, SCAN_B, 0, stream>>>(cntBB, bbpartial);
    k_scanB<<<1, SCAN_B, 0, stream>>>(bbpartial);
    k_fillP2<<<NCH, 256, 0, stream>>>(src, dst, cntBB, bbpartial, stage);
    k_fillB<<<NBK, 256, 0, stream>>>(stage, cntBB, bbpartial, rowptr, dinv, csr16);

    const int gemmGrid = (NN + 63) / 64;  // 782

    // layer 1 agg (zero-LDS, high occupancy): gather xb -> agg1b bf16
    k_agge<DI, false><<<(NN + 31) / 32, 256, 0, stream>>>(xb, csr16, rowptr, dinv,
                                                          nullptr, agg1bu);
    // fused GEMM1+GEMM2 (bf16 sA union, 32KB LDS): agg1b -> h1 (LDS bf16) -> tb
    k_gemm12<<<gemmGrid, 256, 0, stream>>>(agg1b, W1, b1, W2, tbu);

    // layer-2 agg: gather tb, +b2, relu -> h2b (bf16)
    k_agge<DH, true><<<(NN + 15) / 16, 256, 0, stream>>>(tb, csr16, rowptr, dinv, b2, h2b);

    // pool + head
    k_pool3<<<(NN + POOL_CHUNK - 1) / POOL_CHUNK, 256, 0, stream>>>(h2b, batch, pooled);
    k_head<<<1, 256, 0, stream>>>(pooled, gstart, Wf, bf, out);
}